// Round 1
// baseline (96.943 us; speedup 1.0000x reference)
//
#include <hip/hip_runtime.h>

#define DIM 256
#define NNODES 32
#define NMOL 256
#define LHID 3
#define LOUT 2

// LDS row strides chosen: multiple of 4 floats (16B alignment for float4/b128)
// and +4 float skew per row -> rows land on rotating bank offsets.
#define VS 260   // stride for sv/sh (32 rows)
#define WS_ 260  // stride for Wt (32 k-rows x 256 cols)

__launch_bounds__(256, 1)
__global__ void molgnn_kernel(const int* __restrict__ subgraph,
                              const float* __restrict__ adj,
                              const float* __restrict__ emb,
                              const float* __restrict__ w_sub,
                              const float* __restrict__ b_sub,
                              const float* __restrict__ w_out,
                              const float* __restrict__ b_out,
                              const float* __restrict__ w_prop,
                              const float* __restrict__ b_prop,
                              float* __restrict__ out)
{
    __shared__ float sv[NNODES * VS];     // node features (current layer input)
    __shared__ float sh[NNODES * VS];     // post-relu h tile
    __shared__ float Wt[32 * WS_];        // transposed W k-slab: Wt[k][j]
    __shared__ float sa[NNODES * 33];     // 32x32 adjacency block
    __shared__ float sx[2][DIM];          // pooled vector ping-pong
    __shared__ float sred[4];

    const int t  = threadIdx.x;
    const int m  = blockIdx.x;
    const int rg = t >> 5;       // 0..7  row group (4 rows each)
    const int cg = t & 31;       // 0..31 col group
    const int row0 = rg * 4;
    const int cLo = cg * 4;          // cols [0,128)
    const int cHi = 128 + cg * 4;    // cols [128,256)

    // ---------------- gather V = emb[subgraph] into sv ----------------
    {
        const int r  = t >> 3;            // 0..31
        const int cc = (t & 7) * 32;      // 32-col chunk
        const long node = (long)m * NNODES + r;
        const float* src = emb + (long)subgraph[node] * DIM + cc;
        #pragma unroll
        for (int q = 0; q < 8; ++q) {
            float4 v = *(const float4*)(src + q * 4);
            *(float4*)&sv[r * VS + cc + q * 4] = v;
        }
    }
    // ---------------- stage 32x32 diagonal adjacency block ----------------
    {
        const int r  = t >> 3;
        const int p0 = (t & 7) * 4;
        const float* arow = adj + (long)(m * NNODES + r) * 8192 + (long)m * NNODES + p0;
        float4 a = *(const float4*)arow;
        sa[r * 33 + p0 + 0] = a.x;
        sa[r * 33 + p0 + 1] = a.y;
        sa[r * 33 + p0 + 2] = a.z;
        sa[r * 33 + p0 + 3] = a.w;
    }

    // ---------------- 3 hidden layers ----------------
    for (int l = 0; l < LHID; ++l) {
        const float* W    = w_sub + (long)l * DIM * DIM;
        const float* bias = b_sub + l * DIM;

        float acc[4][8];
        #pragma unroll
        for (int c = 0; c < 4; ++c) {
            float blo = bias[cLo + c];
            float bhi = bias[cHi + c];
            #pragma unroll
            for (int r = 0; r < 4; ++r) { acc[r][c] = blo; acc[r][4 + c] = bhi; }
        }

        // GEMM: acc[r][c] += sum_k v[row][k] * W[col][k]
        for (int kt = 0; kt < 8; ++kt) {
            __syncthreads();
            // stage Wt[k][j] = W[j][kt*32+k]  (transpose via registers)
            {
                const float* wrow = W + (long)t * DIM + kt * 32;
                float wv[32];
                #pragma unroll
                for (int q = 0; q < 8; ++q) {
                    float4 v = *(const float4*)(wrow + q * 4);
                    wv[q * 4 + 0] = v.x; wv[q * 4 + 1] = v.y;
                    wv[q * 4 + 2] = v.z; wv[q * 4 + 3] = v.w;
                }
                #pragma unroll
                for (int c = 0; c < 32; ++c) Wt[c * WS_ + t] = wv[c];
            }
            __syncthreads();

            const float* svk = &sv[row0 * VS + kt * 32];
            #pragma unroll 8
            for (int k = 0; k < 32; ++k) {
                float4 wlo = *(const float4*)&Wt[k * WS_ + cLo];
                float4 whi = *(const float4*)&Wt[k * WS_ + cHi];
                #pragma unroll
                for (int r = 0; r < 4; ++r) {
                    float vk = svk[r * VS + k];
                    acc[r][0] += vk * wlo.x; acc[r][1] += vk * wlo.y;
                    acc[r][2] += vk * wlo.z; acc[r][3] += vk * wlo.w;
                    acc[r][4] += vk * whi.x; acc[r][5] += vk * whi.y;
                    acc[r][6] += vk * whi.z; acc[r][7] += vk * whi.w;
                }
            }
        }

        // relu
        #pragma unroll
        for (int r = 0; r < 4; ++r)
            #pragma unroll
            for (int c = 0; c < 8; ++c)
                acc[r][c] = fmaxf(acc[r][c], 0.f);

        // write h tile to sh (prev readers of sh are done: GEMM barriers passed)
        __syncthreads();
        #pragma unroll
        for (int r = 0; r < 4; ++r) {
            *(float4*)&sh[(row0 + r) * VS + cLo] = *(float4*)&acc[r][0];
            *(float4*)&sh[(row0 + r) * VS + cHi] = *(float4*)&acc[r][4];
        }
        __syncthreads();

        // adjacency: acc[r][c] += sum_p A[row][p] * h[p][col]   (residual already in acc)
        for (int p = 0; p < 32; ++p) {
            float4 hlo = *(const float4*)&sh[p * VS + cLo];
            float4 hhi = *(const float4*)&sh[p * VS + cHi];
            #pragma unroll
            for (int r = 0; r < 4; ++r) {
                float a = sa[(row0 + r) * 33 + p];
                acc[r][0] += a * hlo.x; acc[r][1] += a * hlo.y;
                acc[r][2] += a * hlo.z; acc[r][3] += a * hlo.w;
                acc[r][4] += a * hhi.x; acc[r][5] += a * hhi.y;
                acc[r][6] += a * hhi.z; acc[r][7] += a * hhi.w;
            }
        }

        // row L2 norms: reduce over the 32 cg-lanes sharing each row group
        #pragma unroll
        for (int r = 0; r < 4; ++r) {
            float s = 0.f;
            #pragma unroll
            for (int c = 0; c < 8; ++c) s += acc[r][c] * acc[r][c];
            #pragma unroll
            for (int off = 1; off < 32; off <<= 1) s += __shfl_xor(s, off);
            float invn = 1.0f / fmaxf(sqrtf(s), 1e-12f);
            #pragma unroll
            for (int c = 0; c < 8; ++c) acc[r][c] *= invn;
        }

        // write normalized v back to sv (GEMM sv reads finished before sh-write barrier)
        #pragma unroll
        for (int r = 0; r < 4; ++r) {
            *(float4*)&sv[(row0 + r) * VS + cLo] = *(float4*)&acc[r][0];
            *(float4*)&sv[(row0 + r) * VS + cHi] = *(float4*)&acc[r][4];
        }
        // next layer's first kt-barrier makes these writes visible
    }

    __syncthreads();

    // ---------------- pool: mol[d] = sum_i v[i][d] ----------------
    {
        float s = 0.f;
        #pragma unroll
        for (int i = 0; i < NNODES; ++i) s += sv[i * VS + t];
        sx[0][t] = s;
    }
    __syncthreads();

    // ---------------- output MLP (row-local) ----------------
    int cur = 0;
    float x = 0.f;
    for (int l = 0; l < LOUT; ++l) {
        const float* Wr = w_out + (long)l * DIM * DIM + (long)t * DIM;
        float s = b_out[l * DIM + t];
        #pragma unroll 16
        for (int k = 0; k < DIM; k += 4) {
            float4 w4 = *(const float4*)(Wr + k);
            s += w4.x * sx[cur][k + 0] + w4.y * sx[cur][k + 1]
               + w4.z * sx[cur][k + 2] + w4.w * sx[cur][k + 3];
        }
        x = fmaxf(s, 0.f);
        __syncthreads();              // all reads of sx[cur] done
        sx[1 - cur][t] = x;
        __syncthreads();
        cur = 1 - cur;
    }

    // ---------------- final property head ----------------
    {
        float p = x * w_prop[t];
        #pragma unroll
        for (int off = 1; off < 64; off <<= 1) p += __shfl_xor(p, off);
        if ((t & 63) == 0) sred[t >> 6] = p;
        __syncthreads();
        if (t == 0) out[m] = sred[0] + sred[1] + sred[2] + sred[3] + b_prop[0];
    }
}

extern "C" void kernel_launch(void* const* d_in, const int* in_sizes, int n_in,
                              void* d_out, int out_size, void* d_ws, size_t ws_size,
                              hipStream_t stream) {
    const int*   subgraph = (const int*)d_in[0];
    // d_in[1] segment_ids: layout is i/32 by construction; not needed
    const float* adjm     = (const float*)d_in[2];
    const float* emb      = (const float*)d_in[3];
    const float* w_sub    = (const float*)d_in[4];
    const float* b_sub    = (const float*)d_in[5];
    const float* w_out    = (const float*)d_in[6];
    const float* b_out    = (const float*)d_in[7];
    const float* w_prop   = (const float*)d_in[8];
    const float* b_prop   = (const float*)d_in[9];
    float* outp = (float*)d_out;

    molgnn_kernel<<<NMOL, 256, 0, stream>>>(subgraph, adjm, emb, w_sub, b_sub,
                                            w_out, b_out, w_prop, b_prop, outp);
}

// Round 2
// 55.688 us; speedup vs baseline: 1.7408x; 1.7408x over previous
//
#include <hip/hip_runtime.h>

#define NMOL 256
#define VSH 264   // ushort stride, sv hi/lo planes (32 rows x 256 k)  -> 528B rows, 16B aligned
#define TS  40    // ushort stride, shT planes (256 cols x 32 nodes) and adjacency

typedef short bf16x8 __attribute__((ext_vector_type(8)));
typedef float f32x4  __attribute__((ext_vector_type(4)));

__device__ __forceinline__ unsigned short bf_trunc(float f) {
    return (unsigned short)(__float_as_uint(f) >> 16);
}
__device__ __forceinline__ float bf_hif(float f) {
    return __uint_as_float(__float_as_uint(f) & 0xFFFF0000u);
}
__device__ __forceinline__ unsigned short bf_rne(float f) {
    unsigned int u = __float_as_uint(f);
    return (unsigned short)((u + 0x7FFFu + ((u >> 16) & 1u)) >> 16);
}

// Split w_sub (3*256*256 fp32) into bf16 hi (trunc) / lo (rne of residual) planes in d_ws.
__global__ void prep_w_kernel(const float* __restrict__ w,
                              unsigned short* __restrict__ whi,
                              unsigned short* __restrict__ wlo) {
    int i = blockIdx.x * 256 + threadIdx.x;          // 4 elems per thread
    float4 v = ((const float4*)w)[i];
    ushort4 h, lo;
    h.x = bf_trunc(v.x); h.y = bf_trunc(v.y); h.z = bf_trunc(v.z); h.w = bf_trunc(v.w);
    lo.x = bf_rne(v.x - bf_hif(v.x)); lo.y = bf_rne(v.y - bf_hif(v.y));
    lo.z = bf_rne(v.z - bf_hif(v.z)); lo.w = bf_rne(v.w - bf_hif(v.w));
    ((ushort4*)whi)[i] = h;
    ((ushort4*)wlo)[i] = lo;
}

__launch_bounds__(256, 1)
__global__ void molgnn_mfma(const int* __restrict__ subgraph,
                            const float* __restrict__ adj,
                            const float* __restrict__ emb,
                            const float* __restrict__ b_sub,
                            const float* __restrict__ w_out,
                            const float* __restrict__ b_out,
                            const float* __restrict__ w_prop,
                            const float* __restrict__ b_prop,
                            const unsigned short* __restrict__ whi,
                            const unsigned short* __restrict__ wlo,
                            float* __restrict__ out) {
    __shared__ unsigned short svh[32 * VSH];   // v hi plane  [row][k]
    __shared__ unsigned short svl[32 * VSH];   // v lo plane
    __shared__ unsigned short sth[256 * TS];   // h^T hi plane [col][node]
    __shared__ unsigned short stl[256 * TS];   // h^T lo plane
    __shared__ unsigned short sah[32 * TS];    // adjacency block bf16 (exact 0/1)
    __shared__ float srow[4 * 32];
    __shared__ float sinv[32];
    __shared__ float sbias[3 * 256];
    __shared__ float sx[2][256];
    __shared__ float sred[4];

    const int t = threadIdx.x, m = blockIdx.x;
    const int w  = t >> 6;          // wave 0..3 -> col slab of 64
    const int l  = t & 63;
    const int lr = l & 15;          // frag row/col index
    const int lg = l >> 4;          // frag k-group
    const int j0 = w * 64;

    // stage hidden biases
    sbias[t] = b_sub[t]; sbias[256 + t] = b_sub[256 + t]; sbias[512 + t] = b_sub[512 + t];

    // gather emb rows -> sv hi/lo planes
    {
        const int r = t >> 3, c0 = (t & 7) * 32;
        const float* src = emb + (long)subgraph[m * 32 + r] * 256 + c0;
        #pragma unroll
        for (int q = 0; q < 32; q += 4) {
            float4 v = *(const float4*)(src + q);
            unsigned int h01 = (unsigned int)bf_trunc(v.x) | ((unsigned int)bf_trunc(v.y) << 16);
            unsigned int h23 = (unsigned int)bf_trunc(v.z) | ((unsigned int)bf_trunc(v.w) << 16);
            unsigned int l01 = (unsigned int)bf_rne(v.x - bf_hif(v.x)) | ((unsigned int)bf_rne(v.y - bf_hif(v.y)) << 16);
            unsigned int l23 = (unsigned int)bf_rne(v.z - bf_hif(v.z)) | ((unsigned int)bf_rne(v.w - bf_hif(v.w)) << 16);
            *(uint2*)&svh[r * VSH + c0 + q] = make_uint2(h01, h23);
            *(uint2*)&svl[r * VSH + c0 + q] = make_uint2(l01, l23);
        }
    }
    // adjacency diag block -> bf16 (0/1 exact under truncation)
    {
        const int r = t >> 3, p0 = (t & 7) * 4;
        const float* ar = adj + (long)(m * 32 + r) * 8192 + m * 32 + p0;
        float4 a = *(const float4*)ar;
        sah[r * TS + p0 + 0] = bf_trunc(a.x);
        sah[r * TS + p0 + 1] = bf_trunc(a.y);
        sah[r * TS + p0 + 2] = bf_trunc(a.z);
        sah[r * TS + p0 + 3] = bf_trunc(a.w);
    }
    __syncthreads();

    f32x4 acc[2][4];

    for (int layer = 0; layer < 3; ++layer) {
        // C init = bias[col], broadcast over rows
        #pragma unroll
        for (int jt = 0; jt < 4; ++jt) {
            float b = sbias[layer * 256 + j0 + jt * 16 + lr];
            #pragma unroll
            for (int mt = 0; mt < 2; ++mt) {
                acc[mt][jt][0] = b; acc[mt][jt][1] = b; acc[mt][jt][2] = b; acc[mt][jt][3] = b;
            }
        }

        const unsigned short* WH = whi + layer * 65536;
        const unsigned short* WL = wlo + layer * 65536;

        // GEMM1: h = v @ W^T  (split bf16, 3 products), B frags double-buffered from global
        bf16x8 Bh[2][4], Bl[2][4];
        #pragma unroll
        for (int jt = 0; jt < 4; ++jt) {
            int base = (j0 + jt * 16 + lr) * 256 + lg * 8;
            Bh[0][jt] = *(const bf16x8*)(WH + base);
            Bl[0][jt] = *(const bf16x8*)(WL + base);
        }
        #pragma unroll
        for (int kt = 0; kt < 8; ++kt) {
            const int cur = kt & 1, nxt = cur ^ 1;
            if (kt < 7) {
                #pragma unroll
                for (int jt = 0; jt < 4; ++jt) {
                    int base = (j0 + jt * 16 + lr) * 256 + (kt + 1) * 32 + lg * 8;
                    Bh[nxt][jt] = *(const bf16x8*)(WH + base);
                    Bl[nxt][jt] = *(const bf16x8*)(WL + base);
                }
            }
            bf16x8 Ah[2], Al[2];
            #pragma unroll
            for (int mt = 0; mt < 2; ++mt) {
                int off = (mt * 16 + lr) * VSH + kt * 32 + lg * 8;
                Ah[mt] = *(const bf16x8*)&svh[off];
                Al[mt] = *(const bf16x8*)&svl[off];
            }
            #pragma unroll
            for (int mt = 0; mt < 2; ++mt)
                #pragma unroll
                for (int jt = 0; jt < 4; ++jt) {
                    acc[mt][jt] = __builtin_amdgcn_mfma_f32_16x16x32_bf16(Ah[mt], Bh[cur][jt], acc[mt][jt], 0, 0, 0);
                    acc[mt][jt] = __builtin_amdgcn_mfma_f32_16x16x32_bf16(Al[mt], Bh[cur][jt], acc[mt][jt], 0, 0, 0);
                    acc[mt][jt] = __builtin_amdgcn_mfma_f32_16x16x32_bf16(Ah[mt], Bl[cur][jt], acc[mt][jt], 0, 0, 0);
                }
        }

        // relu; stage h^T (hi/lo) for this wave's own col slab (no cross-wave use)
        #pragma unroll
        for (int mt = 0; mt < 2; ++mt)
            #pragma unroll
            for (int jt = 0; jt < 4; ++jt) {
                int col = j0 + jt * 16 + lr;
                float hv[4];
                #pragma unroll
                for (int r = 0; r < 4; ++r) {
                    float h = fmaxf(acc[mt][jt][r], 0.f);
                    acc[mt][jt][r] = h;      // residual stays in C
                    hv[r] = h;
                }
                ushort4 hp, lp;
                hp.x = bf_trunc(hv[0]); hp.y = bf_trunc(hv[1]); hp.z = bf_trunc(hv[2]); hp.w = bf_trunc(hv[3]);
                lp.x = bf_rne(hv[0] - bf_hif(hv[0])); lp.y = bf_rne(hv[1] - bf_hif(hv[1]));
                lp.z = bf_rne(hv[2] - bf_hif(hv[2])); lp.w = bf_rne(hv[3] - bf_hif(hv[3]));
                int off = col * TS + mt * 16 + lg * 4;
                *(ushort4*)&sth[off] = hp;
                *(ushort4*)&stl[off] = lp;
            }

        // GEMM2: acc += A @ h  (A exact bf16; h split -> 2 products). Same-wave LDS, no barrier.
        bf16x8 Aa[2];
        #pragma unroll
        for (int mt = 0; mt < 2; ++mt)
            Aa[mt] = *(const bf16x8*)&sah[(mt * 16 + lr) * TS + lg * 8];
        #pragma unroll
        for (int jt = 0; jt < 4; ++jt) {
            int off = (j0 + jt * 16 + lr) * TS + lg * 8;
            bf16x8 Hh = *(const bf16x8*)&sth[off];
            bf16x8 Hl = *(const bf16x8*)&stl[off];
            #pragma unroll
            for (int mt = 0; mt < 2; ++mt) {
                acc[mt][jt] = __builtin_amdgcn_mfma_f32_16x16x32_bf16(Aa[mt], Hh, acc[mt][jt], 0, 0, 0);
                acc[mt][jt] = __builtin_amdgcn_mfma_f32_16x16x32_bf16(Aa[mt], Hl, acc[mt][jt], 0, 0, 0);
            }
        }

        // row L2 normalize (rows = mt*16 + lg*4 + r; cols split across lr-lanes and waves)
        float ss[2][4];
        #pragma unroll
        for (int mt = 0; mt < 2; ++mt)
            #pragma unroll
            for (int r = 0; r < 4; ++r) {
                float s = 0.f;
                #pragma unroll
                for (int jt = 0; jt < 4; ++jt) { float a = acc[mt][jt][r]; s += a * a; }
                s += __shfl_xor(s, 1); s += __shfl_xor(s, 2);
                s += __shfl_xor(s, 4); s += __shfl_xor(s, 8);
                ss[mt][r] = s;
            }
        if (lr == 0) {
            #pragma unroll
            for (int mt = 0; mt < 2; ++mt)
                #pragma unroll
                for (int r = 0; r < 4; ++r)
                    srow[w * 32 + mt * 16 + lg * 4 + r] = ss[mt][r];
        }
        __syncthreads();
        if (t < 32) {
            float s = srow[t] + srow[32 + t] + srow[64 + t] + srow[96 + t];
            sinv[t] = 1.0f / fmaxf(sqrtf(s), 1e-12f);
        }
        __syncthreads();
        #pragma unroll
        for (int mt = 0; mt < 2; ++mt)
            #pragma unroll
            for (int r = 0; r < 4; ++r) {
                float iv = sinv[mt * 16 + lg * 4 + r];
                #pragma unroll
                for (int jt = 0; jt < 4; ++jt) acc[mt][jt][r] *= iv;
            }
        if (layer < 2) {
            // write normalized v back as next layer's A planes
            #pragma unroll
            for (int mt = 0; mt < 2; ++mt)
                #pragma unroll
                for (int jt = 0; jt < 4; ++jt) {
                    int col = j0 + jt * 16 + lr;
                    #pragma unroll
                    for (int r = 0; r < 4; ++r) {
                        int row = mt * 16 + lg * 4 + r;
                        float vv = acc[mt][jt][r];
                        svh[row * VSH + col] = bf_trunc(vv);
                        svl[row * VSH + col] = bf_rne(vv - bf_hif(vv));
                    }
                }
        }
        __syncthreads();
    }

    // sum-pool per molecule: col totals (each wave owns its 64 cols)
    #pragma unroll
    for (int jt = 0; jt < 4; ++jt) {
        float s = 0.f;
        #pragma unroll
        for (int mt = 0; mt < 2; ++mt)
            #pragma unroll
            for (int r = 0; r < 4; ++r) s += acc[mt][jt][r];
        s += __shfl_xor(s, 16);
        s += __shfl_xor(s, 32);
        if (l < 16) sx[0][j0 + jt * 16 + l] = s;
    }
    __syncthreads();

    // output MLP (row-local fp32)
    int cur = 0;
    float x = 0.f;
    for (int ol = 0; ol < 2; ++ol) {
        const float* Wr = w_out + (long)ol * 256 * 256 + (long)t * 256;
        float s = b_out[ol * 256 + t];
        #pragma unroll 16
        for (int k = 0; k < 256; k += 4) {
            float4 w4 = *(const float4*)(Wr + k);
            s += w4.x * sx[cur][k + 0] + w4.y * sx[cur][k + 1]
               + w4.z * sx[cur][k + 2] + w4.w * sx[cur][k + 3];
        }
        x = fmaxf(s, 0.f);
        __syncthreads();
        sx[1 - cur][t] = x;
        __syncthreads();
        cur = 1 - cur;
    }

    // property head
    {
        float p = x * w_prop[t];
        #pragma unroll
        for (int off = 1; off < 64; off <<= 1) p += __shfl_xor(p, off);
        if ((t & 63) == 0) sred[t >> 6] = p;
        __syncthreads();
        if (t == 0) out[m] = sred[0] + sred[1] + sred[2] + sred[3] + b_prop[0];
    }
}

extern "C" void kernel_launch(void* const* d_in, const int* in_sizes, int n_in,
                              void* d_out, int out_size, void* d_ws, size_t ws_size,
                              hipStream_t stream) {
    const int*   subgraph = (const int*)d_in[0];
    const float* adjm     = (const float*)d_in[2];
    const float* emb      = (const float*)d_in[3];
    const float* w_sub    = (const float*)d_in[4];
    const float* b_sub    = (const float*)d_in[5];
    const float* w_out    = (const float*)d_in[6];
    const float* b_out    = (const float*)d_in[7];
    const float* w_prop   = (const float*)d_in[8];
    const float* b_prop   = (const float*)d_in[9];
    float* outp = (float*)d_out;

    unsigned short* whi = (unsigned short*)d_ws;          // 3*65536 bf16
    unsigned short* wlo = whi + 3 * 65536;                // 3*65536 bf16 (total 786 KB)

    prep_w_kernel<<<192, 256, 0, stream>>>(w_sub, whi, wlo);
    molgnn_mfma<<<NMOL, 256, 0, stream>>>(subgraph, adjm, emb, b_sub,
                                          w_out, b_out, w_prop, b_prop,
                                          whi, wlo, outp);
}

// Round 3
// 53.767 us; speedup vs baseline: 1.8030x; 1.0357x over previous
//
#include <hip/hip_runtime.h>

#define NMOL 256
#define VSH 264   // ushort stride, sv hi/lo planes (32 rows x 256 k)
#define TS  40    // ushort stride, shT planes (256 cols x 32 nodes) and adjacency

typedef short bf16x8 __attribute__((ext_vector_type(8)));
typedef float f32x4  __attribute__((ext_vector_type(4)));

__device__ __forceinline__ unsigned short bf_trunc(float f) {
    return (unsigned short)(__float_as_uint(f) >> 16);
}
__device__ __forceinline__ float bf_hif(float f) {
    return __uint_as_float(__float_as_uint(f) & 0xFFFF0000u);
}
__device__ __forceinline__ unsigned short bf_rne(float f) {
    unsigned int u = __float_as_uint(f);
    return (unsigned short)((u + 0x7FFFu + ((u >> 16) & 1u)) >> 16);
}

// Split w_sub (3*256*256 fp32) into bf16 hi (trunc) / lo (rne of residual) planes in d_ws.
__global__ void prep_w_kernel(const float* __restrict__ w,
                              unsigned short* __restrict__ whi,
                              unsigned short* __restrict__ wlo) {
    int i = blockIdx.x * 256 + threadIdx.x;          // 4 elems per thread
    float4 v = ((const float4*)w)[i];
    ushort4 h, lo;
    h.x = bf_trunc(v.x); h.y = bf_trunc(v.y); h.z = bf_trunc(v.z); h.w = bf_trunc(v.w);
    lo.x = bf_rne(v.x - bf_hif(v.x)); lo.y = bf_rne(v.y - bf_hif(v.y));
    lo.z = bf_rne(v.z - bf_hif(v.z)); lo.w = bf_rne(v.w - bf_hif(v.w));
    ((ushort4*)whi)[i] = h;
    ((ushort4*)wlo)[i] = lo;
}

__launch_bounds__(512, 1)
__global__ void molgnn_mfma(const int* __restrict__ subgraph,
                            const float* __restrict__ adj,
                            const float* __restrict__ emb,
                            const float* __restrict__ b_sub,
                            const float* __restrict__ w_out,
                            const float* __restrict__ b_out,
                            const float* __restrict__ w_prop,
                            const float* __restrict__ b_prop,
                            const unsigned short* __restrict__ whi,
                            const unsigned short* __restrict__ wlo,
                            float* __restrict__ out) {
    __shared__ unsigned short svh[32 * VSH];   // v hi plane  [row][k]
    __shared__ unsigned short svl[32 * VSH];   // v lo plane
    __shared__ unsigned short sth[256 * TS];   // h^T hi plane [col][node]
    __shared__ unsigned short stl[256 * TS];   // h^T lo plane
    __shared__ unsigned short sah[32 * TS];    // adjacency block bf16 (exact 0/1)
    __shared__ float srow[8 * 32];
    __shared__ float sinv[32];
    __shared__ float sbias[3 * 256];
    __shared__ float sx[2][256];
    __shared__ float sxp[2][256];
    __shared__ float sred[4];

    const int t = threadIdx.x, m = blockIdx.x;
    const int w  = t >> 6;          // wave 0..7 -> col slab of 32
    const int l  = t & 63;
    const int lr = l & 15;          // frag row/col index
    const int lg = l >> 4;          // frag k-group
    const int j0 = w * 32;

    // stage hidden biases
    for (int i = t; i < 768; i += 512) sbias[i] = b_sub[i];

    // gather emb rows -> sv hi/lo planes (16 elems per thread)
    {
        const int r = t >> 4, c0 = (t & 15) * 16;
        const float* src = emb + (long)subgraph[m * 32 + r] * 256 + c0;
        #pragma unroll
        for (int q = 0; q < 16; q += 4) {
            float4 v = *(const float4*)(src + q);
            unsigned int h01 = (unsigned int)bf_trunc(v.x) | ((unsigned int)bf_trunc(v.y) << 16);
            unsigned int h23 = (unsigned int)bf_trunc(v.z) | ((unsigned int)bf_trunc(v.w) << 16);
            unsigned int l01 = (unsigned int)bf_rne(v.x - bf_hif(v.x)) | ((unsigned int)bf_rne(v.y - bf_hif(v.y)) << 16);
            unsigned int l23 = (unsigned int)bf_rne(v.z - bf_hif(v.z)) | ((unsigned int)bf_rne(v.w - bf_hif(v.w)) << 16);
            *(uint2*)&svh[r * VSH + c0 + q] = make_uint2(h01, h23);
            *(uint2*)&svl[r * VSH + c0 + q] = make_uint2(l01, l23);
        }
    }
    // adjacency diag block -> bf16 (0/1 exact under truncation)
    {
        const int r = t >> 4, p0 = (t & 15) * 2;
        const float* ar = adj + (long)(m * 32 + r) * 8192 + m * 32 + p0;
        float2 a = *(const float2*)ar;
        sah[r * TS + p0 + 0] = bf_trunc(a.x);
        sah[r * TS + p0 + 1] = bf_trunc(a.y);
    }
    __syncthreads();

    f32x4 acc[2][2];

    for (int layer = 0; layer < 3; ++layer) {
        // C init = bias[col], broadcast over rows
        #pragma unroll
        for (int jt = 0; jt < 2; ++jt) {
            float b = sbias[layer * 256 + j0 + jt * 16 + lr];
            #pragma unroll
            for (int mt = 0; mt < 2; ++mt) {
                acc[mt][jt][0] = b; acc[mt][jt][1] = b; acc[mt][jt][2] = b; acc[mt][jt][3] = b;
            }
        }

        const unsigned short* WH = whi + layer * 65536;
        const unsigned short* WL = wlo + layer * 65536;

        // GEMM1: h = v @ W^T  (split bf16, 3 products), B frags double-buffered from global
        bf16x8 Bh[2][2], Bl[2][2];
        #pragma unroll
        for (int jt = 0; jt < 2; ++jt) {
            int base = (j0 + jt * 16 + lr) * 256 + lg * 8;
            Bh[0][jt] = *(const bf16x8*)(WH + base);
            Bl[0][jt] = *(const bf16x8*)(WL + base);
        }
        #pragma unroll
        for (int kt = 0; kt < 8; ++kt) {
            const int cur = kt & 1, nxt = cur ^ 1;
            if (kt < 7) {
                #pragma unroll
                for (int jt = 0; jt < 2; ++jt) {
                    int base = (j0 + jt * 16 + lr) * 256 + (kt + 1) * 32 + lg * 8;
                    Bh[nxt][jt] = *(const bf16x8*)(WH + base);
                    Bl[nxt][jt] = *(const bf16x8*)(WL + base);
                }
            }
            bf16x8 Ah[2], Al[2];
            #pragma unroll
            for (int mt = 0; mt < 2; ++mt) {
                int off = (mt * 16 + lr) * VSH + kt * 32 + lg * 8;
                Ah[mt] = *(const bf16x8*)&svh[off];
                Al[mt] = *(const bf16x8*)&svl[off];
            }
            #pragma unroll
            for (int mt = 0; mt < 2; ++mt)
                #pragma unroll
                for (int jt = 0; jt < 2; ++jt) {
                    acc[mt][jt] = __builtin_amdgcn_mfma_f32_16x16x32_bf16(Ah[mt], Bh[cur][jt], acc[mt][jt], 0, 0, 0);
                    acc[mt][jt] = __builtin_amdgcn_mfma_f32_16x16x32_bf16(Al[mt], Bh[cur][jt], acc[mt][jt], 0, 0, 0);
                    acc[mt][jt] = __builtin_amdgcn_mfma_f32_16x16x32_bf16(Ah[mt], Bl[cur][jt], acc[mt][jt], 0, 0, 0);
                }
        }

        // relu; stage h^T (hi/lo) for this wave's own col slab (no cross-wave use)
        #pragma unroll
        for (int mt = 0; mt < 2; ++mt)
            #pragma unroll
            for (int jt = 0; jt < 2; ++jt) {
                int col = j0 + jt * 16 + lr;
                float hv[4];
                #pragma unroll
                for (int r = 0; r < 4; ++r) {
                    float h = fmaxf(acc[mt][jt][r], 0.f);
                    acc[mt][jt][r] = h;      // residual stays in C
                    hv[r] = h;
                }
                ushort4 hp, lp;
                hp.x = bf_trunc(hv[0]); hp.y = bf_trunc(hv[1]); hp.z = bf_trunc(hv[2]); hp.w = bf_trunc(hv[3]);
                lp.x = bf_rne(hv[0] - bf_hif(hv[0])); lp.y = bf_rne(hv[1] - bf_hif(hv[1]));
                lp.z = bf_rne(hv[2] - bf_hif(hv[2])); lp.w = bf_rne(hv[3] - bf_hif(hv[3]));
                int off = col * TS + mt * 16 + lg * 4;
                *(ushort4*)&sth[off] = hp;
                *(ushort4*)&stl[off] = lp;
            }

        // GEMM2: acc += A @ h  (A exact bf16; h split -> 2 products). Same-wave LDS, no barrier.
        bf16x8 Aa[2];
        #pragma unroll
        for (int mt = 0; mt < 2; ++mt)
            Aa[mt] = *(const bf16x8*)&sah[(mt * 16 + lr) * TS + lg * 8];
        #pragma unroll
        for (int jt = 0; jt < 2; ++jt) {
            int off = (j0 + jt * 16 + lr) * TS + lg * 8;
            bf16x8 Hh = *(const bf16x8*)&sth[off];
            bf16x8 Hl = *(const bf16x8*)&stl[off];
            #pragma unroll
            for (int mt = 0; mt < 2; ++mt) {
                acc[mt][jt] = __builtin_amdgcn_mfma_f32_16x16x32_bf16(Aa[mt], Hh, acc[mt][jt], 0, 0, 0);
                acc[mt][jt] = __builtin_amdgcn_mfma_f32_16x16x32_bf16(Aa[mt], Hl, acc[mt][jt], 0, 0, 0);
            }
        }

        // row L2 normalize (rows = mt*16 + lg*4 + r; cols split across lr-lanes and 8 waves)
        float ss[2][4];
        #pragma unroll
        for (int mt = 0; mt < 2; ++mt)
            #pragma unroll
            for (int r = 0; r < 4; ++r) {
                float s = 0.f;
                #pragma unroll
                for (int jt = 0; jt < 2; ++jt) { float a = acc[mt][jt][r]; s += a * a; }
                s += __shfl_xor(s, 1); s += __shfl_xor(s, 2);
                s += __shfl_xor(s, 4); s += __shfl_xor(s, 8);
                ss[mt][r] = s;
            }
        if (lr == 0) {
            #pragma unroll
            for (int mt = 0; mt < 2; ++mt)
                #pragma unroll
                for (int r = 0; r < 4; ++r)
                    srow[w * 32 + mt * 16 + lg * 4 + r] = ss[mt][r];
        }
        __syncthreads();
        if (t < 32) {
            float s = 0.f;
            #pragma unroll
            for (int ww = 0; ww < 8; ++ww) s += srow[ww * 32 + t];
            sinv[t] = 1.0f / fmaxf(sqrtf(s), 1e-12f);
        }
        __syncthreads();
        #pragma unroll
        for (int mt = 0; mt < 2; ++mt)
            #pragma unroll
            for (int r = 0; r < 4; ++r) {
                float iv = sinv[mt * 16 + lg * 4 + r];
                #pragma unroll
                for (int jt = 0; jt < 2; ++jt) acc[mt][jt][r] *= iv;
            }
        if (layer < 2) {
            // write normalized v back as next layer's A planes
            #pragma unroll
            for (int mt = 0; mt < 2; ++mt)
                #pragma unroll
                for (int jt = 0; jt < 2; ++jt) {
                    int col = j0 + jt * 16 + lr;
                    #pragma unroll
                    for (int r = 0; r < 4; ++r) {
                        int row = mt * 16 + lg * 4 + r;
                        float vv = acc[mt][jt][r];
                        svh[row * VSH + col] = bf_trunc(vv);
                        svl[row * VSH + col] = bf_rne(vv - bf_hif(vv));
                    }
                }
        }
        __syncthreads();
    }

    // sum-pool per molecule: col totals (each wave owns its 32 cols)
    #pragma unroll
    for (int jt = 0; jt < 2; ++jt) {
        float s = 0.f;
        #pragma unroll
        for (int mt = 0; mt < 2; ++mt)
            #pragma unroll
            for (int r = 0; r < 4; ++r) s += acc[mt][jt][r];
        s += __shfl_xor(s, 16);
        s += __shfl_xor(s, 32);
        if (l < 16) sx[0][j0 + jt * 16 + l] = s;
    }
    __syncthreads();

    // output MLP: col = t&255, split-k over 2 halves
    {
        const int col = t & 255, half = t >> 8;
        int cur = 0;
        for (int ol = 0; ol < 2; ++ol) {
            const float* Wr = w_out + (long)ol * 65536 + (long)col * 256 + half * 128;
            const float* xs = &sx[cur][half * 128];
            float s = 0.f;
            #pragma unroll 8
            for (int k = 0; k < 128; k += 4) {
                float4 w4 = *(const float4*)(Wr + k);
                s += w4.x * xs[k + 0] + w4.y * xs[k + 1]
                   + w4.z * xs[k + 2] + w4.w * xs[k + 3];
            }
            sxp[half][col] = s;
            __syncthreads();
            if (half == 0) {
                float v = sxp[0][col] + sxp[1][col] + b_out[ol * 256 + col];
                sx[1 - cur][col] = fmaxf(v, 0.f);
            }
            __syncthreads();
            cur = 1 - cur;
        }

        // property head (final x is in sx[0])
        float p = 0.f;
        if (t < 256) p = sx[0][t] * w_prop[t];
        #pragma unroll
        for (int off = 1; off < 64; off <<= 1) p += __shfl_xor(p, off);
        if (t < 256 && (t & 63) == 0) sred[t >> 6] = p;
        __syncthreads();
        if (t == 0) out[m] = sred[0] + sred[1] + sred[2] + sred[3] + b_prop[0];
    }
}

extern "C" void kernel_launch(void* const* d_in, const int* in_sizes, int n_in,
                              void* d_out, int out_size, void* d_ws, size_t ws_size,
                              hipStream_t stream) {
    const int*   subgraph = (const int*)d_in[0];
    const float* adjm     = (const float*)d_in[2];
    const float* emb      = (const float*)d_in[3];
    const float* w_sub    = (const float*)d_in[4];
    const float* b_sub    = (const float*)d_in[5];
    const float* w_out    = (const float*)d_in[6];
    const float* b_out    = (const float*)d_in[7];
    const float* w_prop   = (const float*)d_in[8];
    const float* b_prop   = (const float*)d_in[9];
    float* outp = (float*)d_out;

    unsigned short* whi = (unsigned short*)d_ws;          // 3*65536 bf16
    unsigned short* wlo = whi + 3 * 65536;                // 3*65536 bf16

    prep_w_kernel<<<192, 256, 0, stream>>>(w_sub, whi, wlo);
    molgnn_mfma<<<NMOL, 512, 0, stream>>>(subgraph, adjm, emb, b_sub,
                                          w_out, b_out, w_prop, b_prop,
                                          whi, wlo, outp);
}

// Round 4
// 53.237 us; speedup vs baseline: 1.8210x; 1.0100x over previous
//
#include <hip/hip_runtime.h>

#define NMOL 256
#define VSH 264   // ushort stride, sv hi/lo planes (32 rows x 256 k)
#define TS  40    // ushort stride, shT planes (256 cols x 32 nodes) and adjacency

typedef short bf16x8 __attribute__((ext_vector_type(8)));
typedef float f32x4  __attribute__((ext_vector_type(4)));

__device__ __forceinline__ unsigned short bf_trunc(float f) {
    return (unsigned short)(__float_as_uint(f) >> 16);
}
__device__ __forceinline__ float bf_hif(float f) {
    return __uint_as_float(__float_as_uint(f) & 0xFFFF0000u);
}
__device__ __forceinline__ unsigned short bf_rne(float f) {
    unsigned int u = __float_as_uint(f);
    return (unsigned short)((u + 0x7FFFu + ((u >> 16) & 1u)) >> 16);
}

// Split w_sub (3*256*256 fp32) into bf16 hi (trunc) / lo (rne of residual) planes in d_ws.
__global__ void prep_w_kernel(const float* __restrict__ w,
                              unsigned short* __restrict__ whi,
                              unsigned short* __restrict__ wlo) {
    int i = blockIdx.x * 256 + threadIdx.x;          // 4 elems per thread
    float4 v = ((const float4*)w)[i];
    ushort4 h, lo;
    h.x = bf_trunc(v.x); h.y = bf_trunc(v.y); h.z = bf_trunc(v.z); h.w = bf_trunc(v.w);
    lo.x = bf_rne(v.x - bf_hif(v.x)); lo.y = bf_rne(v.y - bf_hif(v.y));
    lo.z = bf_rne(v.z - bf_hif(v.z)); lo.w = bf_rne(v.w - bf_hif(v.w));
    ((ushort4*)whi)[i] = h;
    ((ushort4*)wlo)[i] = lo;
}

__launch_bounds__(1024, 1)
__global__ void molgnn_mfma(const int* __restrict__ subgraph,
                            const float* __restrict__ adj,
                            const float* __restrict__ emb,
                            const float* __restrict__ b_sub,
                            const float* __restrict__ w_out,
                            const float* __restrict__ b_out,
                            const float* __restrict__ w_prop,
                            const float* __restrict__ b_prop,
                            const unsigned short* __restrict__ whi,
                            const unsigned short* __restrict__ wlo,
                            float* __restrict__ out) {
    __shared__ unsigned short svh[32 * VSH];   // v hi plane  [row][k]
    __shared__ unsigned short svl[32 * VSH];   // v lo plane
    __shared__ unsigned short sth[256 * TS];   // h^T hi plane [col][node]
    __shared__ unsigned short stl[256 * TS];   // h^T lo plane
    __shared__ unsigned short sah[32 * TS];    // adjacency block bf16 (exact 0/1)
    __shared__ float srow[16 * 32];
    __shared__ float sinv[32];
    __shared__ float sbias[3 * 256];
    __shared__ float sx[2][256];
    __shared__ float sxp[4][256];
    __shared__ float sred[4];

    const int t = threadIdx.x, m = blockIdx.x;
    const int w  = t >> 6;          // wave 0..15 -> col slab of 16
    const int l  = t & 63;
    const int lr = l & 15;          // frag row/col index
    const int lg = l >> 4;          // frag k-group
    const int j0 = w * 16;

    // ---- early prefetch: layer-0 kt=0 B fragments (in flight during staging) ----
    const int bfr = (j0 + lr) * 256 + lg * 8;  // fragment base within a layer plane
    bf16x8 Bhbuf[2], Blbuf[2];
    Bhbuf[0] = *(const bf16x8*)(whi + bfr);
    Blbuf[0] = *(const bf16x8*)(wlo + bfr);

    // stage hidden biases
    if (t < 768) sbias[t] = b_sub[t];

    // gather emb rows -> sv hi/lo planes (8 elems per thread)
    {
        const int r = t >> 5, c0 = (t & 31) * 8;
        const float* src = emb + (long)subgraph[m * 32 + r] * 256 + c0;
        #pragma unroll
        for (int q = 0; q < 8; q += 4) {
            float4 v = *(const float4*)(src + q);
            unsigned int h01 = (unsigned int)bf_trunc(v.x) | ((unsigned int)bf_trunc(v.y) << 16);
            unsigned int h23 = (unsigned int)bf_trunc(v.z) | ((unsigned int)bf_trunc(v.w) << 16);
            unsigned int l01 = (unsigned int)bf_rne(v.x - bf_hif(v.x)) | ((unsigned int)bf_rne(v.y - bf_hif(v.y)) << 16);
            unsigned int l23 = (unsigned int)bf_rne(v.z - bf_hif(v.z)) | ((unsigned int)bf_rne(v.w - bf_hif(v.w)) << 16);
            *(uint2*)&svh[r * VSH + c0 + q] = make_uint2(h01, h23);
            *(uint2*)&svl[r * VSH + c0 + q] = make_uint2(l01, l23);
        }
    }
    // adjacency diag block -> bf16 (0/1 exact under truncation), 1 elem per thread
    {
        const int r = t >> 5, p = t & 31;
        sah[r * TS + p] = bf_trunc(adj[(long)(m * 32 + r) * 8192 + m * 32 + p]);
    }
    __syncthreads();

    f32x4 acc[2];

    for (int layer = 0; layer < 3; ++layer) {
        // C init = bias[col], broadcast over rows
        {
            float b = sbias[layer * 256 + j0 + lr];
            #pragma unroll
            for (int mt = 0; mt < 2; ++mt) {
                acc[mt][0] = b; acc[mt][1] = b; acc[mt][2] = b; acc[mt][3] = b;
            }
        }

        const unsigned short* WH = whi + layer * 65536;
        const unsigned short* WL = wlo + layer * 65536;
        // next layer's plane (for cross-layer prefetch; layer 2 wraps harmlessly to 0)
        const int nl = (layer < 2) ? layer + 1 : 0;
        const unsigned short* WHn = whi + nl * 65536;
        const unsigned short* WLn = wlo + nl * 65536;

        // GEMM1: h = v @ W^T  (split bf16, 3 products), B frags double-buffered from global
        #pragma unroll
        for (int kt = 0; kt < 8; ++kt) {
            const int cur = kt & 1, nxt = cur ^ 1;
            if (kt < 7) {
                Bhbuf[nxt] = *(const bf16x8*)(WH + bfr + (kt + 1) * 32);
                Blbuf[nxt] = *(const bf16x8*)(WL + bfr + (kt + 1) * 32);
            } else {
                // cross-layer prefetch of next layer's kt=0 (covered by epilogue)
                Bhbuf[nxt] = *(const bf16x8*)(WHn + bfr);
                Blbuf[nxt] = *(const bf16x8*)(WLn + bfr);
            }
            bf16x8 Ah[2], Al[2];
            #pragma unroll
            for (int mt = 0; mt < 2; ++mt) {
                int off = (mt * 16 + lr) * VSH + kt * 32 + lg * 8;
                Ah[mt] = *(const bf16x8*)&svh[off];
                Al[mt] = *(const bf16x8*)&svl[off];
            }
            #pragma unroll
            for (int mt = 0; mt < 2; ++mt) {
                acc[mt] = __builtin_amdgcn_mfma_f32_16x16x32_bf16(Ah[mt], Bhbuf[cur], acc[mt], 0, 0, 0);
                acc[mt] = __builtin_amdgcn_mfma_f32_16x16x32_bf16(Al[mt], Bhbuf[cur], acc[mt], 0, 0, 0);
                acc[mt] = __builtin_amdgcn_mfma_f32_16x16x32_bf16(Ah[mt], Blbuf[cur], acc[mt], 0, 0, 0);
            }
        }

        // relu; stage h^T (hi/lo) for this wave's own 16-col slab (no cross-wave use)
        #pragma unroll
        for (int mt = 0; mt < 2; ++mt) {
            const int col = j0 + lr;
            float hv[4];
            #pragma unroll
            for (int r = 0; r < 4; ++r) {
                float h = fmaxf(acc[mt][r], 0.f);
                acc[mt][r] = h;              // residual stays in C
                hv[r] = h;
            }
            ushort4 hp, lp;
            hp.x = bf_trunc(hv[0]); hp.y = bf_trunc(hv[1]); hp.z = bf_trunc(hv[2]); hp.w = bf_trunc(hv[3]);
            lp.x = bf_rne(hv[0] - bf_hif(hv[0])); lp.y = bf_rne(hv[1] - bf_hif(hv[1]));
            lp.z = bf_rne(hv[2] - bf_hif(hv[2])); lp.w = bf_rne(hv[3] - bf_hif(hv[3]));
            int off = col * TS + mt * 16 + lg * 4;
            *(ushort4*)&sth[off] = hp;
            *(ushort4*)&stl[off] = lp;
        }

        // GEMM2: acc += A @ h  (A exact bf16; h split -> 2 products). Same-wave LDS, no barrier.
        {
            bf16x8 Aa[2];
            #pragma unroll
            for (int mt = 0; mt < 2; ++mt)
                Aa[mt] = *(const bf16x8*)&sah[(mt * 16 + lr) * TS + lg * 8];
            int off = (j0 + lr) * TS + lg * 8;
            bf16x8 Hh = *(const bf16x8*)&sth[off];
            bf16x8 Hl = *(const bf16x8*)&stl[off];
            #pragma unroll
            for (int mt = 0; mt < 2; ++mt) {
                acc[mt] = __builtin_amdgcn_mfma_f32_16x16x32_bf16(Aa[mt], Hh, acc[mt], 0, 0, 0);
                acc[mt] = __builtin_amdgcn_mfma_f32_16x16x32_bf16(Aa[mt], Hl, acc[mt], 0, 0, 0);
            }
        }

        // row L2 normalize (rows = mt*16 + lg*4 + r; cols split across lr-lanes and 16 waves)
        float ss[2][4];
        #pragma unroll
        for (int mt = 0; mt < 2; ++mt)
            #pragma unroll
            for (int r = 0; r < 4; ++r) {
                float a = acc[mt][r];
                float s = a * a;
                s += __shfl_xor(s, 1); s += __shfl_xor(s, 2);
                s += __shfl_xor(s, 4); s += __shfl_xor(s, 8);
                ss[mt][r] = s;
            }
        if (lr == 0) {
            #pragma unroll
            for (int mt = 0; mt < 2; ++mt)
                #pragma unroll
                for (int r = 0; r < 4; ++r)
                    srow[w * 32 + mt * 16 + lg * 4 + r] = ss[mt][r];
        }
        __syncthreads();
        if (t < 32) {
            float s = 0.f;
            #pragma unroll
            for (int ww = 0; ww < 16; ++ww) s += srow[ww * 32 + t];
            sinv[t] = 1.0f / fmaxf(sqrtf(s), 1e-12f);
        }
        __syncthreads();
        #pragma unroll
        for (int mt = 0; mt < 2; ++mt)
            #pragma unroll
            for (int r = 0; r < 4; ++r)
                acc[mt][r] *= sinv[mt * 16 + lg * 4 + r];

        if (layer < 2) {
            // write normalized v back as next layer's A planes
            const int col = j0 + lr;
            #pragma unroll
            for (int mt = 0; mt < 2; ++mt)
                #pragma unroll
                for (int r = 0; r < 4; ++r) {
                    int row = mt * 16 + lg * 4 + r;
                    float vv = acc[mt][r];
                    svh[row * VSH + col] = bf_trunc(vv);
                    svl[row * VSH + col] = bf_rne(vv - bf_hif(vv));
                }
        }
        __syncthreads();
    }

    // sum-pool per molecule: col totals (each wave owns its 16 cols)
    {
        float s = 0.f;
        #pragma unroll
        for (int mt = 0; mt < 2; ++mt)
            #pragma unroll
            for (int r = 0; r < 4; ++r) s += acc[mt][r];
        s += __shfl_xor(s, 16);
        s += __shfl_xor(s, 32);
        if (l < 16) sx[0][j0 + l] = s;
    }
    __syncthreads();

    // output MLP: col = t&255, split-k over 4 quarters
    {
        const int col = t & 255, q = t >> 8;
        int cur = 0;
        for (int ol = 0; ol < 2; ++ol) {
            const float* Wr = w_out + (long)ol * 65536 + (long)col * 256 + q * 64;
            const float* xs = &sx[cur][q * 64];
            float s = 0.f;
            #pragma unroll 8
            for (int k = 0; k < 64; k += 4) {
                float4 w4 = *(const float4*)(Wr + k);
                s += w4.x * xs[k + 0] + w4.y * xs[k + 1]
                   + w4.z * xs[k + 2] + w4.w * xs[k + 3];
            }
            sxp[q][col] = s;
            __syncthreads();
            if (q == 0) {
                float v = sxp[0][col] + sxp[1][col] + sxp[2][col] + sxp[3][col]
                        + b_out[ol * 256 + col];
                sx[1 - cur][col] = fmaxf(v, 0.f);
            }
            __syncthreads();
            cur = 1 - cur;
        }

        // property head (final x is in sx[0])
        float p = 0.f;
        if (t < 256) p = sx[0][t] * w_prop[t];
        #pragma unroll
        for (int off = 1; off < 64; off <<= 1) p += __shfl_xor(p, off);
        if (t < 256 && (t & 63) == 0) sred[t >> 6] = p;
        __syncthreads();
        if (t == 0) out[m] = sred[0] + sred[1] + sred[2] + sred[3] + b_prop[0];
    }
}

extern "C" void kernel_launch(void* const* d_in, const int* in_sizes, int n_in,
                              void* d_out, int out_size, void* d_ws, size_t ws_size,
                              hipStream_t stream) {
    const int*   subgraph = (const int*)d_in[0];
    const float* adjm     = (const float*)d_in[2];
    const float* emb      = (const float*)d_in[3];
    const float* w_sub    = (const float*)d_in[4];
    const float* b_sub    = (const float*)d_in[5];
    const float* w_out    = (const float*)d_in[6];
    const float* b_out    = (const float*)d_in[7];
    const float* w_prop   = (const float*)d_in[8];
    const float* b_prop   = (const float*)d_in[9];
    float* outp = (float*)d_out;

    unsigned short* whi = (unsigned short*)d_ws;          // 3*65536 bf16
    unsigned short* wlo = whi + 3 * 65536;                // 3*65536 bf16

    prep_w_kernel<<<192, 256, 0, stream>>>(w_sub, whi, wlo);
    molgnn_mfma<<<NMOL, 1024, 0, stream>>>(subgraph, adjm, emb, b_sub,
                                           w_out, b_out, w_prop, b_prop,
                                           whi, wlo, outp);
}

// Round 5
// 49.277 us; speedup vs baseline: 1.9673x; 1.0804x over previous
//
#include <hip/hip_runtime.h>

#define NMOL 256
#define VSH 264   // ushort stride, sv hi/lo planes (32 rows x 256 k)
#define TS  40    // ushort stride, shT planes (256 cols x 32 nodes) and adjacency

typedef short bf16x8 __attribute__((ext_vector_type(8)));
typedef float f32x4  __attribute__((ext_vector_type(4)));

__device__ __forceinline__ unsigned short bf_trunc(float f) {
    return (unsigned short)(__float_as_uint(f) >> 16);
}
__device__ __forceinline__ float bf_hif(float f) {
    return __uint_as_float(__float_as_uint(f) & 0xFFFF0000u);
}
__device__ __forceinline__ unsigned short bf_rne(float f) {
    unsigned int u = __float_as_uint(f);
    return (unsigned short)((u + 0x7FFFu + ((u >> 16) & 1u)) >> 16);
}

// split 8 fp32 (two float4) into bf16 hi (trunc) / lo (rne residual) fragments
__device__ __forceinline__ void split8(float4 a, float4 b, bf16x8& hi, bf16x8& lo) {
    float v0[4] = {a.x, a.y, a.z, a.w};
    float v1[4] = {b.x, b.y, b.z, b.w};
    union { unsigned int u[4]; bf16x8 s; } H, L;
    #pragma unroll
    for (int i = 0; i < 2; ++i) {
        unsigned int u0 = __float_as_uint(v0[2*i]), u1 = __float_as_uint(v0[2*i+1]);
        H.u[i] = (u0 >> 16) | (u1 & 0xFFFF0000u);
        unsigned int l0 = bf_rne(v0[2*i]   - __uint_as_float(u0 & 0xFFFF0000u));
        unsigned int l1 = bf_rne(v0[2*i+1] - __uint_as_float(u1 & 0xFFFF0000u));
        L.u[i] = l0 | (l1 << 16);
    }
    #pragma unroll
    for (int i = 0; i < 2; ++i) {
        unsigned int u0 = __float_as_uint(v1[2*i]), u1 = __float_as_uint(v1[2*i+1]);
        H.u[2+i] = (u0 >> 16) | (u1 & 0xFFFF0000u);
        unsigned int l0 = bf_rne(v1[2*i]   - __uint_as_float(u0 & 0xFFFF0000u));
        unsigned int l1 = bf_rne(v1[2*i+1] - __uint_as_float(u1 & 0xFFFF0000u));
        L.u[2+i] = l0 | (l1 << 16);
    }
    hi = H.s; lo = L.s;
}

__launch_bounds__(1024, 1)
__global__ void molgnn_mfma(const int* __restrict__ subgraph,
                            const float* __restrict__ adj,
                            const float* __restrict__ emb,
                            const float* __restrict__ w_sub,
                            const float* __restrict__ b_sub,
                            const float* __restrict__ w_out,
                            const float* __restrict__ b_out,
                            const float* __restrict__ w_prop,
                            const float* __restrict__ b_prop,
                            float* __restrict__ out) {
    __shared__ unsigned short svh[32 * VSH];   // v hi plane  [row][k]
    __shared__ unsigned short svl[32 * VSH];   // v lo plane
    __shared__ unsigned short sth[256 * TS];   // h^T hi plane [col][node]
    __shared__ unsigned short stl[256 * TS];   // h^T lo plane
    __shared__ unsigned short sah[32 * TS];    // adjacency block bf16 (exact 0/1)
    __shared__ float srow[16 * 32];
    __shared__ float sinv[32];
    __shared__ float sbias[3 * 256];
    __shared__ float sx[2][256];
    __shared__ float sxp[4][256];
    __shared__ float sred[4];

    const int t = threadIdx.x, m = blockIdx.x;
    const int w  = t >> 6;          // wave 0..15 -> col slab of 16
    const int l  = t & 63;
    const int lr = l & 15;          // frag row/col index
    const int lg = l >> 4;          // frag k-group
    const int j0 = w * 16;

    // W fragment base (fp32 plane): row (j0+lr), k-offset lg*8
    const int bfr = (j0 + lr) * 256 + lg * 8;

    // ---- early prefetch: layer-0 kt=0 raw fp32 W fragment ----
    float4 Bva[2], Bvb[2];
    Bva[0] = *(const float4*)(w_sub + bfr);
    Bvb[0] = *(const float4*)(w_sub + bfr + 4);

    // stage hidden biases
    if (t < 768) sbias[t] = b_sub[t];

    // gather emb rows -> sv hi/lo planes (8 elems per thread)
    {
        const int r = t >> 5, c0 = (t & 31) * 8;
        const float* src = emb + (long)subgraph[m * 32 + r] * 256 + c0;
        #pragma unroll
        for (int q = 0; q < 8; q += 4) {
            float4 v = *(const float4*)(src + q);
            unsigned int h01 = (unsigned int)bf_trunc(v.x) | ((unsigned int)bf_trunc(v.y) << 16);
            unsigned int h23 = (unsigned int)bf_trunc(v.z) | ((unsigned int)bf_trunc(v.w) << 16);
            unsigned int l01 = (unsigned int)bf_rne(v.x - bf_hif(v.x)) | ((unsigned int)bf_rne(v.y - bf_hif(v.y)) << 16);
            unsigned int l23 = (unsigned int)bf_rne(v.z - bf_hif(v.z)) | ((unsigned int)bf_rne(v.w - bf_hif(v.w)) << 16);
            *(uint2*)&svh[r * VSH + c0 + q] = make_uint2(h01, h23);
            *(uint2*)&svl[r * VSH + c0 + q] = make_uint2(l01, l23);
        }
    }
    // adjacency diag block -> bf16 (0/1 exact under truncation), 1 elem per thread
    {
        const int r = t >> 5, p = t & 31;
        sah[r * TS + p] = bf_trunc(adj[(long)(m * 32 + r) * 8192 + m * 32 + p]);
    }
    __syncthreads();

    f32x4 acc[2];

    for (int layer = 0; layer < 3; ++layer) {
        // C init = bias[col], broadcast over rows
        {
            float b = sbias[layer * 256 + j0 + lr];
            #pragma unroll
            for (int mt = 0; mt < 2; ++mt) {
                acc[mt][0] = b; acc[mt][1] = b; acc[mt][2] = b; acc[mt][3] = b;
            }
        }

        const float* WP = w_sub + layer * 65536;
        const int nl = (layer < 2) ? layer + 1 : 0;   // layer 2 wraps harmlessly
        const float* WPn = w_sub + nl * 65536;

        // GEMM1: h = v @ W^T  (split bf16, 3 products); raw fp32 W double-buffered,
        // hi/lo split done in-register (bit-identical to the old prep-kernel planes)
        #pragma unroll
        for (int kt = 0; kt < 8; ++kt) {
            const int cur = kt & 1, nxt = cur ^ 1;
            if (kt < 7) {
                Bva[nxt] = *(const float4*)(WP + bfr + (kt + 1) * 32);
                Bvb[nxt] = *(const float4*)(WP + bfr + (kt + 1) * 32 + 4);
            } else {
                // cross-layer prefetch of next layer's kt=0 (covered by epilogue)
                Bva[nxt] = *(const float4*)(WPn + bfr);
                Bvb[nxt] = *(const float4*)(WPn + bfr + 4);
            }
            bf16x8 Bh, Bl;
            split8(Bva[cur], Bvb[cur], Bh, Bl);
            bf16x8 Ah[2], Al[2];
            #pragma unroll
            for (int mt = 0; mt < 2; ++mt) {
                int off = (mt * 16 + lr) * VSH + kt * 32 + lg * 8;
                Ah[mt] = *(const bf16x8*)&svh[off];
                Al[mt] = *(const bf16x8*)&svl[off];
            }
            #pragma unroll
            for (int mt = 0; mt < 2; ++mt) {
                acc[mt] = __builtin_amdgcn_mfma_f32_16x16x32_bf16(Ah[mt], Bh, acc[mt], 0, 0, 0);
                acc[mt] = __builtin_amdgcn_mfma_f32_16x16x32_bf16(Al[mt], Bh, acc[mt], 0, 0, 0);
                acc[mt] = __builtin_amdgcn_mfma_f32_16x16x32_bf16(Ah[mt], Bl, acc[mt], 0, 0, 0);
            }
        }

        // relu; stage h^T (hi/lo) for this wave's own 16-col slab (no cross-wave use)
        #pragma unroll
        for (int mt = 0; mt < 2; ++mt) {
            const int col = j0 + lr;
            float hv[4];
            #pragma unroll
            for (int r = 0; r < 4; ++r) {
                float h = fmaxf(acc[mt][r], 0.f);
                acc[mt][r] = h;              // residual stays in C
                hv[r] = h;
            }
            ushort4 hp, lp;
            hp.x = bf_trunc(hv[0]); hp.y = bf_trunc(hv[1]); hp.z = bf_trunc(hv[2]); hp.w = bf_trunc(hv[3]);
            lp.x = bf_rne(hv[0] - bf_hif(hv[0])); lp.y = bf_rne(hv[1] - bf_hif(hv[1]));
            lp.z = bf_rne(hv[2] - bf_hif(hv[2])); lp.w = bf_rne(hv[3] - bf_hif(hv[3]));
            int off = col * TS + mt * 16 + lg * 4;
            *(ushort4*)&sth[off] = hp;
            *(ushort4*)&stl[off] = lp;
        }

        // GEMM2: acc += A @ h  (A exact bf16; h split -> 2 products). Same-wave LDS, no barrier.
        {
            bf16x8 Aa[2];
            #pragma unroll
            for (int mt = 0; mt < 2; ++mt)
                Aa[mt] = *(const bf16x8*)&sah[(mt * 16 + lr) * TS + lg * 8];
            int off = (j0 + lr) * TS + lg * 8;
            bf16x8 Hh = *(const bf16x8*)&sth[off];
            bf16x8 Hl = *(const bf16x8*)&stl[off];
            #pragma unroll
            for (int mt = 0; mt < 2; ++mt) {
                acc[mt] = __builtin_amdgcn_mfma_f32_16x16x32_bf16(Aa[mt], Hh, acc[mt], 0, 0, 0);
                acc[mt] = __builtin_amdgcn_mfma_f32_16x16x32_bf16(Aa[mt], Hl, acc[mt], 0, 0, 0);
            }
        }

        // row L2 normalize (rows = mt*16 + lg*4 + r; cols split across lr-lanes and 16 waves)
        float ss[2][4];
        #pragma unroll
        for (int mt = 0; mt < 2; ++mt)
            #pragma unroll
            for (int r = 0; r < 4; ++r) {
                float a = acc[mt][r];
                float s = a * a;
                s += __shfl_xor(s, 1); s += __shfl_xor(s, 2);
                s += __shfl_xor(s, 4); s += __shfl_xor(s, 8);
                ss[mt][r] = s;
            }
        if (lr == 0) {
            #pragma unroll
            for (int mt = 0; mt < 2; ++mt)
                #pragma unroll
                for (int r = 0; r < 4; ++r)
                    srow[w * 32 + mt * 16 + lg * 4 + r] = ss[mt][r];
        }
        __syncthreads();
        if (t < 32) {
            float s = 0.f;
            #pragma unroll
            for (int ww = 0; ww < 16; ++ww) s += srow[ww * 32 + t];
            sinv[t] = 1.0f / fmaxf(sqrtf(s), 1e-12f);
        }
        __syncthreads();
        #pragma unroll
        for (int mt = 0; mt < 2; ++mt)
            #pragma unroll
            for (int r = 0; r < 4; ++r)
                acc[mt][r] *= sinv[mt * 16 + lg * 4 + r];

        if (layer < 2) {
            // write normalized v back as next layer's A planes
            const int col = j0 + lr;
            #pragma unroll
            for (int mt = 0; mt < 2; ++mt)
                #pragma unroll
                for (int r = 0; r < 4; ++r) {
                    int row = mt * 16 + lg * 4 + r;
                    float vv = acc[mt][r];
                    svh[row * VSH + col] = bf_trunc(vv);
                    svl[row * VSH + col] = bf_rne(vv - bf_hif(vv));
                }
        }
        __syncthreads();
    }

    // sum-pool per molecule: col totals (each wave owns its 16 cols)
    {
        float s = 0.f;
        #pragma unroll
        for (int mt = 0; mt < 2; ++mt)
            #pragma unroll
            for (int r = 0; r < 4; ++r) s += acc[mt][r];
        s += __shfl_xor(s, 16);
        s += __shfl_xor(s, 32);
        if (l < 16) sx[0][j0 + l] = s;
    }
    __syncthreads();

    // output MLP: col = t&255, split-k over 4 quarters
    {
        const int col = t & 255, q = t >> 8;
        int cur = 0;
        for (int ol = 0; ol < 2; ++ol) {
            const float* Wr = w_out + (long)ol * 65536 + (long)col * 256 + q * 64;
            const float* xs = &sx[cur][q * 64];
            float s = 0.f;
            #pragma unroll 8
            for (int k = 0; k < 64; k += 4) {
                float4 w4 = *(const float4*)(Wr + k);
                s += w4.x * xs[k + 0] + w4.y * xs[k + 1]
                   + w4.z * xs[k + 2] + w4.w * xs[k + 3];
            }
            sxp[q][col] = s;
            __syncthreads();
            if (q == 0) {
                float v = sxp[0][col] + sxp[1][col] + sxp[2][col] + sxp[3][col]
                        + b_out[ol * 256 + col];
                sx[1 - cur][col] = fmaxf(v, 0.f);
            }
            __syncthreads();
            cur = 1 - cur;
        }

        // property head (final x is in sx[0])
        float p = 0.f;
        if (t < 256) p = sx[0][t] * w_prop[t];
        #pragma unroll
        for (int off = 1; off < 64; off <<= 1) p += __shfl_xor(p, off);
        if (t < 256 && (t & 63) == 0) sred[t >> 6] = p;
        __syncthreads();
        if (t == 0) out[m] = sred[0] + sred[1] + sred[2] + sred[3] + b_prop[0];
    }
}

extern "C" void kernel_launch(void* const* d_in, const int* in_sizes, int n_in,
                              void* d_out, int out_size, void* d_ws, size_t ws_size,
                              hipStream_t stream) {
    const int*   subgraph = (const int*)d_in[0];
    const float* adjm     = (const float*)d_in[2];
    const float* emb      = (const float*)d_in[3];
    const float* w_sub    = (const float*)d_in[4];
    const float* b_sub    = (const float*)d_in[5];
    const float* w_out    = (const float*)d_in[6];
    const float* b_out    = (const float*)d_in[7];
    const float* w_prop   = (const float*)d_in[8];
    const float* b_prop   = (const float*)d_in[9];
    float* outp = (float*)d_out;

    molgnn_mfma<<<NMOL, 1024, 0, stream>>>(subgraph, adjm, emb, w_sub, b_sub,
                                           w_out, b_out, w_prop, b_prop, outp);
}